// Round 11
// baseline (328.568 us; speedup 1.0000x reference)
//
#include <hip/hip_runtime.h>
#include <stdint.h>

// Problem constants (B=64, P=24564, 21 classes)
#define NC 21
#define BATCH 64
#define PRI 24564
#define SLABS 32              // slabs per batch row
#define SLABR 768             // rows per slab (last slab: 756 valid)
#define GBLK (BATCH * SLABS)  // 2048 logical slabs
#define SENT 0xFFFFFFFFu

// float4 with 4-byte alignment (conf rows are 84B-strided, only dword-aligned)
typedef float f4a4 __attribute__((ext_vector_type(4), aligned(4)));

__device__ __forceinline__ float sl1f(float p, float t) {
    float d = fabsf(p - t);
    return d < 1.0f ? 0.5f * d * d : d - 0.5f;
}

// monotonic float -> uint key map (order-preserving)
__device__ __forceinline__ unsigned int f2k(float v) {
    unsigned int u = __float_as_uint(v);
    return (u & 0x80000000u) ? ~u : (u | 0x80000000u);
}

// selection key from packed (ce, hlce|posbit); pos -> f2k(0.0) = 0x80000000
__device__ __forceinline__ unsigned int chkey(float2 ch) {
    unsigned hb = __float_as_uint(ch.y);
    return (hb & 0x80000000u) ? 0x80000000u : f2k(ch.x);
}

// 256-thread block reduce (4 waves of 64). Valid on tid==0 only.
__device__ __forceinline__ double blockReduce(double v, double* sred) {
    #pragma unroll
    for (int off = 32; off > 0; off >>= 1)
        v += __shfl_down(v, off, 64);
    const int wid = threadIdx.x >> 6, lane = threadIdx.x & 63;
    __syncthreads();
    if (lane == 0) sred[wid] = v;
    __syncthreads();
    double r = 0.0;
    if (threadIdx.x == 0) r = sred[0] + sred[1] + sred[2] + sred[3];
    return r;
}

// Fused front-end: 4096 blocks, role by parity (even = conf-CE, odd = smooth-L1).
// k_ce is latency-bound (~1.8 TB/s on 84-B-strided conf reads; LDS staging twice
// proved neutral), k_sl1 streams dense. Interleaving roles co-schedules both wave
// types per CU -> time ~ max, not sum (r10: serialized back-to-back on stream).
// Bodies are byte-identical to the r10-verified k_ce / k_sl1.
__global__ __launch_bounds__(256, 4) void k_main2(
    const float* __restrict__ loc_data, const float* __restrict__ conf_data,
    const float* __restrict__ has_lp_data, const float* __restrict__ size_lp_data,
    const float* __restrict__ offset_data, const float* __restrict__ loc_t,
    const int* __restrict__ conf_t, const int* __restrict__ has_lp_t,
    const float* __restrict__ size_lp_t, const float* __restrict__ offset_t,
    float* __restrict__ wsf /* = (float*)ws_ch */,
    double* __restrict__ partPN, double* __restrict__ partL)
{
    __shared__ double sred[4];
    const int tid = threadIdx.x;
    const int w = blockIdx.x >> 1;            // logical slab 0..2047
    const int b = w >> 5, s = w & 31;
    const bool isCE = (blockIdx.x & 1) == 0;

    int pr[3]; bool vld[3];
    #pragma unroll
    for (int i = 0; i < 3; ++i) {
        int p = s * SLABR + i * 256 + tid;
        vld[i] = p < PRI;
        pr[i] = vld[i] ? p : PRI - 1;   // clamp: loads unconditional, safe
    }
    const unsigned rb = (unsigned)b * PRI;

    if (isCE) {
        // ---------------- conf CE half ----------------
        int ct[3];
        #pragma unroll
        for (int i = 0; i < 3; ++i) ct[i] = conf_t[rb + pr[i]];
        f4a4 cw[3][5]; float c20[3], gg[3];
        #pragma unroll
        for (int i = 0; i < 3; ++i) {
            const float* crow = conf_data + (long)(rb + pr[i]) * NC;
            #pragma unroll
            for (int j = 0; j < 5; ++j) cw[i][j] = ((const f4a4*)crow)[j];
            c20[i] = crow[20];
            gg[i] = crow[ct[i]];
        }
        int myp = 0, myn = 0;
        #pragma unroll
        for (int i = 0; i < 3; ++i) {
            float m = c20[i];
            #pragma unroll
            for (int j = 0; j < 5; ++j)
                m = fmaxf(m, fmaxf(fmaxf(cw[i][j].x, cw[i][j].y), fmaxf(cw[i][j].z, cw[i][j].w)));
            float sum = __expf(c20[i] - m);
            #pragma unroll
            for (int j = 0; j < 5; ++j)
                sum += __expf(cw[i][j].x - m) + __expf(cw[i][j].y - m)
                     + __expf(cw[i][j].z - m) + __expf(cw[i][j].w - m);
            const float ce = m + __logf(sum) - gg[i];
            if (vld[i]) wsf[2u * (rb + pr[i])] = ce;
            const bool pos = ct[i] > 0;
            myp += (vld[i] && pos) ? 1 : 0;
            myn += (vld[i] && !pos && f2k(ce) != 0x80000000u) ? 1 : 0;
        }
        double v;
        v = blockReduce((double)myp, sred);
        if (tid == 0) partPN[0 * GBLK + w] = v;   // pos count
        v = blockReduce((double)myn, sred);
        if (tid == 0) partPN[1 * GBLK + w] = v;   // nonzero-key negative count
    } else {
        // ---------------- smooth-L1 / has_lp half ----------------
        int ct[3], hl[3]; float4 lp[3], lt[3]; float2 sp2[3], st2[3], op2[3], ot2[3], hh[3];
        #pragma unroll
        for (int i = 0; i < 3; ++i) {
            const unsigned r = rb + pr[i];
            ct[i] = conf_t[r];
            hl[i] = has_lp_t[r];
            lp[i] = ((const float4*)loc_data)[r];
            lt[i] = ((const float4*)loc_t)[r];
            sp2[i] = ((const float2*)size_lp_data)[r];
            st2[i] = ((const float2*)size_lp_t)[r];
            op2[i] = ((const float2*)offset_data)[r];
            ot2[i] = ((const float2*)offset_t)[r];
            hh[i] = ((const float2*)has_lp_data)[r];
        }
        double aL = 0.0, aS = 0.0, aO = 0.0;
        #pragma unroll
        for (int i = 0; i < 3; ++i) {
            const bool pos = ct[i] > 0;
            float ll = sl1f(lp[i].x, lt[i].x) + sl1f(lp[i].y, lt[i].y)
                     + sl1f(lp[i].z, lt[i].z) + sl1f(lp[i].w, lt[i].w);
            float ls = sl1f(sp2[i].x, st2[i].x) + sl1f(sp2[i].y, st2[i].y);
            float lo = sl1f(op2[i].x, ot2[i].x) + sl1f(op2[i].y, ot2[i].y);
            const float pf = (vld[i] && pos) ? 1.f : 0.f;
            const float hf = (hl[i] != 0) ? 1.f : 0.f;
            aL += (double)(pf * ll);
            aS += (double)(pf * hf * ls);
            aO += (double)(pf * hf * lo);
            float hm = fmaxf(hh[i].x, hh[i].y);
            float hs = __expf(hh[i].x - hm) + __expf(hh[i].y - hm);
            float hlce = fmaxf(hm + __logf(hs) - (hl[i] != 0 ? hh[i].y : hh[i].x), 0.0f);
            unsigned hb = __float_as_uint(hlce) | (pos ? 0x80000000u : 0u);
            if (vld[i]) wsf[2u * (rb + pr[i]) + 1u] = __uint_as_float(hb);
        }
        double v;
        v = blockReduce(aL, sred); if (tid == 0) partL[0 * GBLK + w] = v;
        v = blockReduce(aS, sred); if (tid == 0) partL[1 * GBLK + w] = v;
        v = blockReduce(aO, sred); if (tid == 0) partL[2 * GBLK + w] = v;
    }
}

// Threshold decision per batch (64 tiny blocks). Common path (K>M on this data):
// reads 64 doubles, writes T/need. Radix fallback kept correct (dead here).
// (r10-verified.)
__global__ __launch_bounds__(256) void k_thr(
    const float2* __restrict__ ws_ch, const double* __restrict__ partPN,
    unsigned* __restrict__ selT, int* __restrict__ needed)
{
    const int b = blockIdx.x, tid = threadIdx.x;
    __shared__ double sred[4];
    __shared__ int shist[4096];
    __shared__ int sct[256];
    __shared__ unsigned s_dig;
    __shared__ int s_rem;
    __shared__ int s_K, s_M;

    double np = blockReduce((tid < SLABS) ? partPN[0 * GBLK + b * SLABS + tid] : 0.0, sred);
    double mm = blockReduce((tid < SLABS) ? partPN[1 * GBLK + b * SLABS + tid] : 0.0, sred);
    if (tid == 0) {
        int K = 3 * (int)(np + 0.5); if (K > PRI - 1) K = PRI - 1;
        s_K = K; s_M = (int)(mm + 0.5);
    }
    __syncthreads();
    const int K = s_K, M = s_M;

    if (K <= 0) { if (tid == 0) { selT[b] = SENT; needed[b] = 0; } return; }
    if (K > M)  { if (tid == 0) { selT[b] = 0x80000000u; needed[b] = K - M; } return; }

    // ---- rare path: 3-round LDS radix on CE keys (never taken on this data) ----
    const float2* row = ws_ch + (unsigned)b * PRI;
    for (int k = tid; k < 4096; k += 256) shist[k] = 0;
    __syncthreads();
    for (int p = tid; p < PRI; p += 256) {
        unsigned key = chkey(row[p]);
        if (key != 0x80000000u) atomicAdd(&shist[key >> 20], 1);
    }
    __syncthreads();
    {
        int h[16]; int ctn = 0;
        #pragma unroll
        for (int j = 0; j < 16; ++j) { h[j] = shist[tid * 16 + j]; ctn += h[j]; }
        sct[tid] = ctn;
        __syncthreads();
        #pragma unroll
        for (int off = 1; off < 256; off <<= 1) {   // suffix sum
            int v = (tid + off < 256) ? sct[tid + off] : 0;
            __syncthreads();
            sct[tid] += v;
            __syncthreads();
        }
        const int Sa = (tid < 255) ? sct[tid + 1] : 0;
        int cum = Sa;
        #pragma unroll
        for (int j = 15; j >= 0; --j) {
            int c2 = cum + h[j];
            if (c2 >= K && cum < K) { s_dig = (unsigned)(tid * 16 + j); s_rem = K - cum; }
            cum = c2;
        }
        __syncthreads();
    }
    unsigned pref = s_dig; int rem = s_rem;
    __syncthreads();

    // refine 1: 1024 bins on bits 19..10 where key>>20 == pref
    for (int k = tid; k < 1024; k += 256) shist[k] = 0;
    __syncthreads();
    for (int p = tid; p < PRI; p += 256) {
        unsigned key = chkey(row[p]);
        if (key != 0x80000000u && (key >> 20) == pref)
            atomicAdd(&shist[(key >> 10) & 1023], 1);
    }
    __syncthreads();
    {
        int h4[4]; int c4 = 0;
        #pragma unroll
        for (int j = 0; j < 4; ++j) { h4[j] = shist[tid * 4 + j]; c4 += h4[j]; }
        sct[tid] = c4;
        __syncthreads();
        #pragma unroll
        for (int off = 1; off < 256; off <<= 1) {
            int v = (tid + off < 256) ? sct[tid + off] : 0;
            __syncthreads();
            sct[tid] += v;
            __syncthreads();
        }
        const int Sa = (tid < 255) ? sct[tid + 1] : 0;
        int cum = Sa;
        #pragma unroll
        for (int j = 3; j >= 0; --j) {
            int c2 = cum + h4[j];
            if (c2 >= rem && cum < rem) { s_dig = (unsigned)(tid * 4 + j); s_rem = rem - cum; }
            cum = c2;
        }
        __syncthreads();
    }
    pref = (pref << 10) | s_dig; rem = s_rem;
    __syncthreads();

    // refine 2: low 10 bits where key>>10 == pref
    for (int k = tid; k < 1024; k += 256) shist[k] = 0;
    __syncthreads();
    for (int p = tid; p < PRI; p += 256) {
        unsigned key = chkey(row[p]);
        if (key != 0x80000000u && (key >> 10) == pref)
            atomicAdd(&shist[key & 1023], 1);
    }
    __syncthreads();
    {
        int h4[4]; int c4 = 0;
        #pragma unroll
        for (int j = 0; j < 4; ++j) { h4[j] = shist[tid * 4 + j]; c4 += h4[j]; }
        sct[tid] = c4;
        __syncthreads();
        #pragma unroll
        for (int off = 1; off < 256; off <<= 1) {
            int v = (tid + off < 256) ? sct[tid + off] : 0;
            __syncthreads();
            sct[tid] += v;
            __syncthreads();
        }
        const int Sa = (tid < 255) ? sct[tid + 1] : 0;
        int cum = Sa;
        #pragma unroll
        for (int j = 3; j >= 0; --j) {
            int c2 = cum + h4[j];
            if (c2 >= rem && cum < rem) { s_dig = (unsigned)(tid * 4 + j); s_rem = rem - cum; }
            cum = c2;
        }
        __syncthreads();
    }
    if (tid == 0) { selT[b] = (pref << 10) | s_dig; needed[b] = s_rem; }
}

// Per-slab: tie count (key==T) + selected-core sums (pos || key>T) + tie-negative
// sums. 2048 blocks — full-GPU parallel. (r10-verified.)
__global__ __launch_bounds__(256) void k_sel2(
    const float2* __restrict__ ws_ch, const unsigned* __restrict__ selT,
    int* __restrict__ cntT, double* __restrict__ sums)
{
    __shared__ double sred[4];
    const int tid = threadIdx.x;
    const int b = blockIdx.x >> 5, s = blockIdx.x & 31;
    const unsigned T = selT[b];
    double aC = 0.0, aH = 0.0, tC = 0.0, tH = 0.0, cc = 0.0;
    #pragma unroll
    for (int i = 0; i < 3; ++i) {
        const int p = s * SLABR + i * 256 + tid;
        if (p < PRI) {
            float2 ch = ws_ch[(unsigned)b * PRI + p];
            unsigned hb = __float_as_uint(ch.y);
            const bool pos = (hb >> 31) != 0;
            const unsigned key = pos ? 0x80000000u : f2k(ch.x);
            const float hlv = __uint_as_float(hb & 0x7fffffffu);
            if (pos || key > T) { aC += (double)ch.x; aH += (double)hlv; }
            if (key == T) {
                cc += 1.0;
                if (!pos) { tC += (double)ch.x; tH += (double)hlv; }
            }
        }
    }
    double v;
    v = blockReduce(aC, sred); if (tid == 0) sums[0 * GBLK + blockIdx.x] = v;
    v = blockReduce(aH, sred); if (tid == 0) sums[1 * GBLK + blockIdx.x] = v;
    v = blockReduce(tC, sred); if (tid == 0) sums[2 * GBLK + blockIdx.x] = v;
    v = blockReduce(tH, sred); if (tid == 0) sums[3 * GBLK + blockIdx.x] = v;
    v = blockReduce(cc, sred); if (tid == 0) cntT[blockIdx.x] = (int)(v + 0.5);
}

// Per batch: find cutoff slab from tie counts, scan it for the needed-th tie,
// add tie-negative partials, emit (loss_c, loss_has_lp). (r10-verified.)
__global__ __launch_bounds__(256) void k_cut(
    const float2* __restrict__ ws_ch, const unsigned* __restrict__ selT,
    const int* __restrict__ needed, const int* __restrict__ cntT,
    const double* __restrict__ sums, double* __restrict__ lossCH)
{
    const int b = blockIdx.x, tid = threadIdx.x;
    __shared__ double sred[4];
    __shared__ int scnt_s[32];
    __shared__ int s_sl, s_loc, s_found;
    __shared__ int wtot[4];
    const int need = needed[b];
    const unsigned T = selT[b];

    if (tid < 32) scnt_s[tid] = cntT[b * 32 + tid];
    __syncthreads();
    if (tid == 0) {
        int sl = 32, loc = 0, cum = 0;
        if (need > 0) {
            for (int s2 = 0; s2 < 32; ++s2) {
                int c2 = scnt_s[s2];
                if (cum + c2 >= need) { sl = s2; loc = need - cum; break; }
                cum += c2;
            }
        }
        s_sl = sl; s_loc = loc; s_found = -1;
    }
    __syncthreads();
    const int sl = s_sl, loc = s_loc;

    // base: all selected-core sums + tie-neg sums for slabs fully before sl
    double aC = 0.0, aH = 0.0;
    if (tid < 32) {
        aC = sums[0 * GBLK + b * 32 + tid] + (tid < sl ? sums[2 * GBLK + b * 32 + tid] : 0.0);
        aH = sums[1 * GBLK + b * 32 + tid] + (tid < sl ? sums[3 * GBLK + b * 32 + tid] : 0.0);
    }
    double totC = blockReduce(aC, sred);
    double totH = blockReduce(aH, sred);

    if (sl < 32) {
        // pass 1: find cutoff = global index of the loc-th key==T row in slab sl
        int run = 0;
        for (int i = 0; i < 3; ++i) {
            const int p = sl * SLABR + i * 256 + tid;
            bool eq = false;
            if (p < PRI) eq = (chkey(ws_ch[(unsigned)b * PRI + p]) == T);
            const unsigned long long m = __ballot(eq);
            const int lane = tid & 63, wid = tid >> 6;
            if (lane == 0) wtot[wid] = __popcll(m);
            const int mex = __popcll(m & ((1ull << lane) - 1ull));
            __syncthreads();
            int woff = 0;
            for (int w = 0; w < wid; ++w) woff += wtot[w];
            if (eq && (run + woff + mex + 1 == loc)) s_found = p;
            __syncthreads();
            run += wtot[0] + wtot[1] + wtot[2] + wtot[3];
            __syncthreads();
        }
        const int cutoff = s_found;
        // pass 2: tie-negative sums within slab sl with p <= cutoff
        double pC = 0.0, pH = 0.0;
        for (int i = 0; i < 3; ++i) {
            const int p = sl * SLABR + i * 256 + tid;
            if (p < PRI && p <= cutoff) {
                float2 ch = ws_ch[(unsigned)b * PRI + p];
                unsigned hb = __float_as_uint(ch.y);
                const bool pos = (hb >> 31) != 0;
                const unsigned key = pos ? 0x80000000u : f2k(ch.x);
                if (!pos && key == T) {
                    pC += (double)ch.x;
                    pH += (double)__uint_as_float(hb & 0x7fffffffu);
                }
            }
        }
        double v1 = blockReduce(pC, sred);
        double v2 = blockReduce(pH, sred);
        if (tid == 0) { totC += v1; totH += v2; }
    }
    if (tid == 0) { lossCH[b] = totC; lossCH[64 + b] = totH; }
}

// Sum partials, divide by N, emit 5 outputs. (r10-verified.)
__global__ __launch_bounds__(256) void k_final(
    const double* __restrict__ partL, const double* __restrict__ partPN,
    const double* __restrict__ lossCH, float* __restrict__ out)
{
    __shared__ double sred[4];
    const int tid = threadIdx.x;
    double s[3];
    #pragma unroll
    for (int k = 0; k < 3; ++k) {
        double a = 0.0;
        for (int t = tid; t < GBLK; t += 256) a += partL[k * GBLK + t];
        s[k] = blockReduce(a, sred);
    }
    double a = 0.0;
    for (int t = tid; t < GBLK; t += 256) a += partPN[t];
    double n = blockReduce(a, sred);
    double lc = (tid < BATCH) ? lossCH[tid] : 0.0;
    lc = blockReduce(lc, sred);
    double lh = (tid < BATCH) ? lossCH[64 + tid] : 0.0;
    lh = blockReduce(lh, sred);
    if (tid == 0) {
        out[0] = (float)(s[0] / n);   // loss_l
        out[1] = (float)(lc / n);     // loss_c
        out[2] = (float)(s[1] / n);   // loss_size_lp
        out[3] = (float)(s[2] / n);   // loss_offset
        out[4] = (float)(lh / n);     // loss_has_lp
    }
}

extern "C" void kernel_launch(void* const* d_in, const int* in_sizes, int n_in,
                              void* d_out, int out_size, void* d_ws, size_t ws_size,
                              hipStream_t stream)
{
    const float* loc_data     = (const float*)d_in[0];
    const float* conf_data    = (const float*)d_in[1];
    const float* has_lp_data  = (const float*)d_in[2];
    const float* size_lp_data = (const float*)d_in[3];
    const float* offset_data  = (const float*)d_in[4];
    const float* loc_t        = (const float*)d_in[5];
    const int*   conf_t       = (const int*)d_in[6];
    const int*   has_lp_t     = (const int*)d_in[7];
    const float* size_lp_t    = (const float*)d_in[8];
    const float* offset_t     = (const float*)d_in[9];
    float* out = (float*)d_out;

    char* ws = (char*)d_ws;
    unsigned* selT   = (unsigned*)(ws + 0);      // 64 u32
    int* needed      = (int*)(ws + 512);         // 64 int
    int* cntT        = (int*)(ws + 1536);        // 2048 int (8 KB)
    double* partL    = (double*)(ws + 16384);    // 3*2048 doubles (48 KB)
    double* partPN   = (double*)(ws + 65536);    // 2*2048 doubles (32 KB)
    double* sums     = (double*)(ws + 131072);   // 4*2048 doubles (64 KB)
    double* lossCH   = (double*)(ws + 262144);   // 128 doubles
    float2* ws_ch    = (float2*)(ws + 1704960);  // NROWS float2 (~12.6 MB)
    float*  wsf      = (float*)ws_ch;

    // No memsets: every workspace word consumed is written unconditionally
    // by an earlier kernel in the same graph.
    k_main2<<<2 * GBLK, 256, 0, stream>>>(loc_data, conf_data, has_lp_data,
                                          size_lp_data, offset_data, loc_t,
                                          conf_t, has_lp_t, size_lp_t, offset_t,
                                          wsf, partPN, partL);
    k_thr<<<BATCH, 256, 0, stream>>>(ws_ch, partPN, selT, needed);
    k_sel2<<<GBLK, 256, 0, stream>>>(ws_ch, selT, cntT, sums);
    k_cut<<<BATCH, 256, 0, stream>>>(ws_ch, selT, needed, cntT, sums, lossCH);
    k_final<<<1, 256, 0, stream>>>(partL, partPN, lossCH, out);
}